// Round 10
// baseline (143.464 us; speedup 1.0000x reference)
//
#include <hip/hip_runtime.h>

// ContrasPQ forward = per-(b,p) nearest-code lookup.
// out[b, p*8 .. p*8+7] = codebook[p, argmin_k ||v[b,p]-c[p,k]||^2, :]
//
// R10: MFMA approx scores + gap test; exact rescore ONLY on ambiguity.
//   Scores: g~ = (vh+vm+vl)(ch+cm+cl) - vl*cl - 0.5||c||^2 via 2 chained
//   mfma_f32_16x16x32_bf16 (3-term bf16 split; R7 pairing), bias as C-input.
//   |g~ - g_chain| <= E ~ 7e-6. Decision: branchless per-lane top-2+index
//   (5 ops/value), DPP top-2 merge across the 16-lane group. If
//   top1-top2 > THR=4e-5 (>2E): answer = approx top-1, provably equal to
//   the exact-chain argmax. Else (rare ~1.2%/query, group-uniform branch):
//   rescore all 256 codes from global codebook (L2-hot) with the exact f32
//   chain that PASSED on HW in R9 (absmax 0.0), DPP max/min-index pick.
//
// R9 post-mortem: correct but 72us > R2's 62us. (a) flag-scan granularity:
// any-lane-hit executes a wave-wide rescore body -> ~26 bodies/wave, ~500
// instrs of scan+exec-churn; (b) occupancy 12 waves/CU (27.6KB LDS + 120
// regs). Fixes: no flags (gap test), no LDS in decision, drop lds_code/
// lds_v (33KB -> 4 blocks/CU), bias via MFMA C-input, XOR-swizzled lds_B
// staging writes (986K conflict cycles -> ~0).
//
// Layouts (HW-verified lineage): A row = lane&15, B col = lane&15,
// (lane-group,elem)->k bijection shared by A/B; C/D col=lane&15,
// row=(lane>>4)*4+reg (m89/m91; R9 passed end-to-end on this).

typedef float f32x4  __attribute__((ext_vector_type(4)));
typedef short bf16x8 __attribute__((ext_vector_type(8)));

namespace {
constexpr int kB   = 8192;
constexpr int kEMB = 768;
constexpr int kP   = 96;
constexpr int kK   = 256;
constexpr int kD   = 8;
constexpr int QPB  = 64;   // queries per block (4 waves x 16)
}

#define PQ_THR 4.0e-5f     // gap threshold > 2*E

// Manual RN-even f32->bf16 (headerless; data has no NaN/inf).
__device__ __forceinline__ short bf16_rn(float x)
{
    unsigned u = __float_as_uint(x);
    unsigned r = u + 0x7FFFu + ((u >> 16) & 1u);
    return (short)(r >> 16);
}
__device__ __forceinline__ float bf16_f32(short s)
{
    return __uint_as_float(((unsigned)(unsigned short)s) << 16);
}

// Butterfly max/min over each 16-lane group (xor1, xor2, xor7, xor15 via
// quad_perm/half_mirror/mirror) — HW-proven in R9.
__device__ __forceinline__ float dpp_max16(float x)
{
    int y;
    y = __builtin_amdgcn_update_dpp(__float_as_int(x), __float_as_int(x),
                                    0xB1, 0xF, 0xF, true);
    x = fmaxf(x, __int_as_float(y));
    y = __builtin_amdgcn_update_dpp(__float_as_int(x), __float_as_int(x),
                                    0x4E, 0xF, 0xF, true);
    x = fmaxf(x, __int_as_float(y));
    y = __builtin_amdgcn_update_dpp(__float_as_int(x), __float_as_int(x),
                                    0x141, 0xF, 0xF, true);
    x = fmaxf(x, __int_as_float(y));
    y = __builtin_amdgcn_update_dpp(__float_as_int(x), __float_as_int(x),
                                    0x140, 0xF, 0xF, true);
    x = fmaxf(x, __int_as_float(y));
    return x;
}

__device__ __forceinline__ int dpp_min16(int x)
{
    int y;
    y = __builtin_amdgcn_update_dpp(x, x, 0xB1, 0xF, 0xF, true);
    x = min(x, y);
    y = __builtin_amdgcn_update_dpp(x, x, 0x4E, 0xF, 0xF, true);
    x = min(x, y);
    y = __builtin_amdgcn_update_dpp(x, x, 0x141, 0xF, 0xF, true);
    x = min(x, y);
    y = __builtin_amdgcn_update_dpp(x, x, 0x140, 0xF, 0xF, true);
    x = min(x, y);
    return x;
}

// One butterfly step of cross-lane top-2 (+argmax index) merge.
template <int CTRL>
__device__ __forceinline__ void merge_step(float& t1, float& t2, int& idx)
{
    const float y1 = __int_as_float(__builtin_amdgcn_update_dpp(
        __float_as_int(t1), __float_as_int(t1), CTRL, 0xF, 0xF, true));
    const float y2 = __int_as_float(__builtin_amdgcn_update_dpp(
        __float_as_int(t2), __float_as_int(t2), CTRL, 0xF, 0xF, true));
    const int yi = __builtin_amdgcn_update_dpp(idx, idx, CTRL, 0xF, 0xF, true);
    const bool gt = y1 > t1;
    t2 = fmaxf(fminf(t1, y1), fmaxf(t2, y2));   // exact merged second-best
    t1 = fmaxf(t1, y1);
    idx = gt ? yi : idx;
}

// Decision for query row hi*4+I: approx argmax + gap test; exact global
// rescore iff ambiguous. Returns group-uniform winning code index.
template <int I>
__device__ __forceinline__ int decide(const f32x4 (&acc)[16], int colq,
                                      const float* vrow0, const float* cb_p,
                                      const float* h_lds)
{
    float t1 = acc[0][I];
    float t2 = -__builtin_inff();
    int   idx = colq;                        // code 0*16+colq
#pragma unroll
    for (int m = 1; m < 16; ++m) {
        const float v = acc[m][I];
        const bool gt = v > t1;              // strict: keeps lower m
        t2 = fmaxf(fminf(v, t1), t2);
        t1 = fmaxf(t1, v);
        idx = gt ? ((m * 16) | colq) : idx;
    }
    merge_step<0xB1>(t1, t2, idx);           // xor1
    merge_step<0x4E>(t1, t2, idx);           // xor2
    merge_step<0x141>(t1, t2, idx);          // half_mirror (xor7)
    merge_step<0x140>(t1, t2, idx);          // mirror (xor15)

    if (t1 - t2 <= PQ_THR) {   // rare, group-uniform: exact full rescore
        const float* vq = vrow0 + I * kEMB;
        const f32x4 va = *reinterpret_cast<const f32x4*>(vq);
        const f32x4 vb = *reinterpret_cast<const f32x4*>(vq + 4);
        float bs = -__builtin_inff();
        int   bk = 1024;
#pragma unroll
        for (int m = 0; m < 16; ++m) {
            const int kc = m * 16 + colq;
            const f32x4* cr = reinterpret_cast<const f32x4*>(cb_p + kc * kD);
            const f32x4 c0 = cr[0];
            const f32x4 c1 = cr[1];
            // EXACT f32 chain (R9-proven: absmax 0.0 on all 786K cells)
            float s = fmaf(c0.x, va.x, h_lds[kc]);
            s = fmaf(c0.y, va.y, s);
            s = fmaf(c0.z, va.z, s);
            s = fmaf(c0.w, va.w, s);
            s = fmaf(c1.x, vb.x, s);
            s = fmaf(c1.y, vb.y, s);
            s = fmaf(c1.z, vb.z, s);
            s = fmaf(c1.w, vb.w, s);
            if (s > bs) { bs = s; bk = kc; }   // strict >: lowest k
        }
        const float S = dpp_max16(bs);
        idx = dpp_min16((bs == S) ? bk : 1024);
    }
    return idx;
}

__global__ __launch_bounds__(256, 4)
void pq_mfma_kernel(const float* __restrict__ vecs,
                    const float* __restrict__ codebook,
                    float* __restrict__ out)
{
    // B fragments: [tile 16][frag 2][grp 4][col 16][8 bf16] = 32 KB.
    // Staging writes XOR-swizzled by ((tile&3)<<4) shorts to kill the 4-way
    // write conflict; reads apply the same (per-tile-uniform) XOR.
    __shared__ alignas(16) short lds_B[16 * 2 * 512];
    __shared__ alignas(16) float lds_h[kK];   // -0.5*||c||^2

    const int p = blockIdx.y;
    const int t = threadIdx.x;
    const int l = t & 63;
    const int colq = l & 15;   // A row / B col / C col within tile
    const int hi   = l >> 4;   // k-block term group
    const int w    = t >> 6;   // wave id

    const float* cb_p = codebook + (size_t)p * kK * kD;

    // ---- stage codebook[p]: thread t <-> code t (coalesced) ----
    {
        const f32x4* cb4 = reinterpret_cast<const f32x4*>(cb_p);
        f32x4 ca = cb4[2 * t];
        f32x4 cbv = cb4[2 * t + 1];
        float cc[8] = {ca.x, ca.y, ca.z, ca.w, cbv.x, cbv.y, cbv.z, cbv.w};
        bf16x8 ph, pm, pl;
        float c2 = 0.0f;
#pragma unroll
        for (int j = 0; j < 8; ++j) {
            float x  = cc[j];
            short h  = bf16_rn(x);
            float d1 = x - bf16_f32(h);
            short m_ = bf16_rn(d1);
            short lo = bf16_rn(d1 - bf16_f32(m_));
            ph[j] = h; pm[j] = m_; pl[j] = lo;
            c2 = fmaf(x, x, c2);
        }
        lds_h[t] = -0.5f * c2;
        const int tile = t >> 4, col = t & 15;
        const int swz = (tile & 3) << 4;
        // MFMA#0 B groups [ch,cm,ch,cm]; MFMA#1 B groups [cl,ch,cl,cm]
#pragma unroll
        for (int g = 0; g < 4; ++g) {
            const bf16x8 v0 = (g & 1) ? pm : ph;
            const bf16x8 v1 = (g == 0 || g == 2) ? pl : ((g == 1) ? ph : pm);
            *reinterpret_cast<bf16x8*>(
                &lds_B[(((tile * 2 + 0) * 512) + g * 128 + col * 8) ^ swz]) = v0;
            *reinterpret_cast<bf16x8*>(
                &lds_B[(((tile * 2 + 1) * 512) + g * 128 + col * 8) ^ swz]) = v1;
        }
    }

    // ---- A fragments: wave w handles queries qbase..qbase+15 ----
    const int qrow = blockIdx.x * QPB + w * 16 + colq;
    bf16x8 a0, a1;
    {
        const float* vp = vecs + (size_t)qrow * kEMB + p * kD;
        f32x4 va = *reinterpret_cast<const f32x4*>(vp);
        f32x4 vb = *reinterpret_cast<const f32x4*>(vp + 4);
        float vv[8] = {va.x, va.y, va.z, va.w, vb.x, vb.y, vb.z, vb.w};
#pragma unroll
        for (int j = 0; j < 8; ++j) {
            float x  = vv[j];
            short h  = bf16_rn(x);
            float d1 = x - bf16_f32(h);
            short m_ = bf16_rn(d1);
            short lo = bf16_rn(d1 - bf16_f32(m_));
            // MFMA#0 A groups [vh,vh,vm,vm]; MFMA#1 A groups [vh,vl,vm,vl]
            a0[j] = (hi < 2) ? h : m_;
            a1[j] = (hi == 0) ? h : ((hi == 2) ? m_ : lo);
        }
    }
    // #0 -> vh*ch + vh*cm + vm*ch + vm*cm ; #1 -> vh*cl + vl*ch + vm*cl + vl*cm
    // Sum = (vh+vm+vl)(ch+cm+cl) - vl*cl  (vl*cl ~ 2^-32, negligible)

    __syncthreads();

    // ---- 16 tiles x 2 chained MFMAs, bias as C-input ----
    f32x4 acc[16];
#pragma unroll
    for (int m = 0; m < 16; ++m) {
        const int swz = (m & 3) << 4;
        const bf16x8 b0 = *reinterpret_cast<const bf16x8*>(
            &lds_B[(((m * 2 + 0) * 512) + l * 8) ^ swz]);
        const bf16x8 b1 = *reinterpret_cast<const bf16x8*>(
            &lds_B[(((m * 2 + 1) * 512) + l * 8) ^ swz]);
        const float hb = lds_h[m * 16 + colq];   // bias of code m*16+colq
        const f32x4 hc = {hb, hb, hb, hb};
        f32x4 t0 = __builtin_amdgcn_mfma_f32_16x16x32_bf16(a0, b0, hc, 0, 0, 0);
        acc[m]   = __builtin_amdgcn_mfma_f32_16x16x32_bf16(a1, b1, t0, 0, 0, 0);
    }

    // ---- decision per query row (branchless fast path + rare rescore) ----
    const float* vrow0 = vecs +
        (size_t)(blockIdx.x * QPB + w * 16 + hi * 4) * kEMB + p * kD;
    const int k0 = decide<0>(acc, colq, vrow0, cb_p, lds_h);
    const int k1 = decide<1>(acc, colq, vrow0, cb_p, lds_h);
    const int k2 = decide<2>(acc, colq, vrow0, cb_p, lds_h);
    const int k3 = decide<3>(acc, colq, vrow0, cb_p, lds_h);

    // ---- epilogue: lanes 0..7 of each group write its 4 queries ----
    if (colq < 8) {
        const int ka = (colq & 2) ? k1 : k0;
        const int kb = (colq & 2) ? k3 : k2;
        const int kq = (colq & 4) ? kb : ka;
        const int row = blockIdx.x * QPB + w * 16 + (hi << 2) + (colq >> 1);
        const f32x4* cr = reinterpret_cast<const f32x4*>(
            cb_p + (size_t)kq * kD) + (colq & 1);
        f32x4* op = reinterpret_cast<f32x4*>(
            out + (size_t)row * kEMB + p * kD) + (colq & 1);
        *op = *cr;
    }
}

extern "C" void kernel_launch(void* const* d_in, const int* in_sizes, int n_in,
                              void* d_out, int out_size, void* d_ws, size_t ws_size,
                              hipStream_t stream)
{
    const float* vecs     = (const float*)d_in[0];
    const float* codebook = (const float*)d_in[1];
    float* out            = (float*)d_out;

    dim3 grid(kB / QPB, kP, 1);   // (128, 96)
    dim3 block(256, 1, 1);
    hipLaunchKernelGGL(pq_mfma_kernel, grid, block, 0, stream,
                       vecs, codebook, out);
}